// Round 8
// baseline (1806.930 us; speedup 1.0000x reference)
//
#include <hip/hip_runtime.h>
#include <math.h>

// LstmCellRudder persistent MFMA kernel, round 15.
// B=256, T=512, D=160 (obs128+act32), H=512, gates 4H=2048, K=672.
// NEW vs R14: RING DEGREE 16 -> 8 (structural).
//   Counter back-computation: step = 1800 active cycles (MfmaUtil) at
//   ~705 MHz effective clock; 72% is wait = max-of-16 skew x poll quantum.
//   Micro-cuts (R14) flat -> shrink the communicating set instead.
// Grid 128 blocks x 256 threads (4 waves, 1 block/CU). 16 rings x 8 blocks,
// each block owns 64 j-columns (N=256 gate rows, M=16, K=672):
//   - afrag 4 tiles/wave = 336 VGPR (weights stay VGPR-resident; 450 total,
//     fits 512 @ 1 wave/SIMD). MFMA/wave 42 -> 84 per step.
//   - 8-way ring: 32 flags, max-of-8 skew, 16 blocks/XCD (L2 contention /2),
//     x-staging duplication 16x -> 8x (FETCH halves).
//   - publish = one 8B store/lane (4 h-halves); same fragment layout,
//     same workgroup-scope L2-resident protocol (R12-verified).
//   - y: each block produces 2 batch rows (waves {0,1} batch0, {2,3} batch1).

namespace {
constexpr int kT = 512, kH = 512;

typedef _Float16 v8h __attribute__((ext_vector_type(8)));
typedef float v4f __attribute__((ext_vector_type(4)));
typedef unsigned long long ull;
typedef ull v2u __attribute__((ext_vector_type(2)));

// Ring loads: L1-bypass. sys -> IF$-coherent; pure -> served by shared L2.
__device__ __forceinline__ ull ld64sc(const ull* p, bool sys) {
    return sys ? __hip_atomic_load(p, __ATOMIC_RELAXED, __HIP_MEMORY_SCOPE_SYSTEM)
               : __hip_atomic_load(p, __ATOMIC_RELAXED, __HIP_MEMORY_SCOPE_AGENT);
}
__device__ __forceinline__ unsigned ld32sc(const unsigned* p, bool sys) {
    return sys ? __hip_atomic_load(p, __ATOMIC_RELAXED, __HIP_MEMORY_SCOPE_SYSTEM)
               : __hip_atomic_load(p, __ATOMIC_RELAXED, __HIP_MEMORY_SCOPE_AGENT);
}
// Ring stores: pure rings stay in the shared XCD L2 (WORKGROUP scope);
// mixed rings write through (SYSTEM).
__device__ __forceinline__ void st32sc(unsigned* p, unsigned v, bool sys) {
    if (sys) __hip_atomic_store(p, v, __ATOMIC_RELAXED, __HIP_MEMORY_SCOPE_SYSTEM);
    else     __hip_atomic_store(p, v, __ATOMIC_RELAXED, __HIP_MEMORY_SCOPE_WORKGROUP);
}
__device__ __forceinline__ void st64sc(ull* p, ull v, bool sys) {
    if (sys) __hip_atomic_store(p, v, __ATOMIC_RELAXED, __HIP_MEMORY_SCOPE_SYSTEM);
    else     __hip_atomic_store(p, v, __ATOMIC_RELAXED, __HIP_MEMORY_SCOPE_WORKGROUP);
}
__device__ __forceinline__ unsigned ld_sys32(const unsigned* p) {
    return __hip_atomic_load(p, __ATOMIC_RELAXED, __HIP_MEMORY_SCOPE_SYSTEM);
}

// tanh for the (unscaled) cell state; exp2-based, exact at +-inf.
__device__ __forceinline__ float tanhff(float x) {
    return fmaf(-2.0f,
                __builtin_amdgcn_rcpf(__builtin_amdgcn_exp2f(x * 2.885390082f) + 1.0f),
                1.0f);
}

// h0 -> fragment-layout hfA: per ring 16KB; chunk ck (=j>>5) at ck*1024;
// slot = (qf*16 + b) ^ ck holds halfs e=0..7 = h[b][ck*32 + qf*8 + e].
__global__ void lstm_init(const float* __restrict__ h0, _Float16* __restrict__ hfA,
                          unsigned* __restrict__ ctrl) {
    int i = blockIdx.x * blockDim.x + threadIdx.x;  // 131072 = B*H
    int bb = i >> 9, j = i & 511;
    int bgrp = bb >> 4, b = bb & 15;
    int ck = j >> 5, jl = j & 31, qf = jl >> 3, e = jl & 7;
    int slot = (qf * 16 + b) ^ ck;
    hfA[bgrp * 8192 + ck * 512 + slot * 8 + e] = (_Float16)h0[i];
    if (i < 1152) ctrl[i] = 0u;  // flags[16*64] + regcnt[8] + regtotal
}

__global__ __launch_bounds__(256, 1) void lstm_persist(
    const float* __restrict__ obs, const float* __restrict__ act,
    const float* __restrict__ Wih, const float* __restrict__ Whh,
    const float* __restrict__ bih, const float* __restrict__ bhh,
    const float* __restrict__ Wout, const float* __restrict__ bout_p,
    const float* __restrict__ c0,
    _Float16* __restrict__ hfA, _Float16* __restrict__ hfB,
    unsigned* __restrict__ ctrl, float* __restrict__ out) {

    // LDS: x double buffer 2x5KB, h fragment double buffer 2x16KB.
    __shared__ __align__(16) char xbuf[2][5 * 1024];
    __shared__ __align__(16) char hbuf[2][16 * 1024];
    __shared__ float ypart[2][4];
    __shared__ float ytail[4];
    __shared__ int sh_role[3];  // ring, jg, sys

    const int tid = threadIdx.x;
    const int w = tid >> 6, ln = tid & 63;   // 4 waves
    const int lm = ln & 15, q = ln >> 4;     // MFMA lane decomposition

    unsigned* flags = ctrl;              // [16 rings][64] (32 used: 8 blk x 4 wv)
    unsigned* regcnt = ctrl + 1024;      // [8]
    unsigned* regtotal = ctrl + 1032;    // [1]

    // ---- runtime XCD-aware role negotiation (groups of 8 blocks) ----
    if (tid == 0) {
        int x = __builtin_amdgcn_s_getreg(20 | (31 << 11)) & 7;  // HW_REG_XCC_ID
        unsigned slot = atomicAdd(&regcnt[x], 1u);
        asm volatile("s_waitcnt vmcnt(0)" ::: "memory");
        atomicAdd(regtotal, 1u);
        while (ld_sys32(regtotal) < 128u) __builtin_amdgcn_s_sleep(8);
        unsigned cnt[8];
#pragma unroll
        for (int i = 0; i < 8; ++i) cnt[i] = ld_sys32(&regcnt[i]);
        int pure_base = 0, total_pure = 0, lbase = 0;
        for (int i = 0; i < 8; ++i) {
            if (i < x) { pure_base += cnt[i] >> 3; lbase += cnt[i] & 7; }
            total_pure += cnt[i] >> 3;
        }
        int px8 = (int)(cnt[x] >> 3) * 8;
        int bg, jv, sv;
        if ((int)slot < px8) {
            bg = pure_base + ((int)slot >> 3); jv = slot & 7; sv = 0;
        } else {
            int lr = lbase + ((int)slot - px8);
            bg = total_pure + (lr >> 3); jv = lr & 7; sv = 1;
        }
        sh_role[0] = bg; sh_role[1] = jv; sh_role[2] = sv;
    }
    __syncthreads();
    const int bgrp = sh_role[0], jg = sh_role[1];  // jg in [0,8)
    const bool sysS = sh_role[2] != 0;
    const int yb0 = bgrp * 16 + jg * 2;            // two output batch rows
    unsigned* myflags = flags + bgrp * 64;

    // ---- persistent A fragments: 4 tiles/wave; tile ti covers
    // j-local = w*16 + (rr)*4 + ti for tile-row rr = lm>>2, gate = lm&3.
    // Lane (lm,q) acc reg g = gate g of j-local = w*16 + q*4 + ti, batch lm.
    // Prescale rows: i,f,o by -log2(e); g by +2*log2(e) (exp2 epilogue).
    v8h afrag[4][21];
    {
        const int jj = lm >> 2, gt = lm & 3;
        const float scg = (gt == 2) ? 2.885390082f : -1.442695041f;
#pragma unroll
        for (int ti = 0; ti < 4; ++ti) {
            const int grow = gt * kH + jg * 64 + w * 16 + jj * 4 + ti;
#pragma unroll
            for (int kc = 0; kc < 21; ++kc) {
                const int k0 = kc * 32 + q * 8;
                const float* src = (k0 < 160) ? (Wih + grow * 160 + k0)
                                              : (Whh + (size_t)grow * kH + (k0 - 160));
                float4 A = *(const float4*)src;
                float4 Bv = *(const float4*)(src + 4);
                v8h f;
                f[0] = (_Float16)(A.x * scg);  f[1] = (_Float16)(A.y * scg);
                f[2] = (_Float16)(A.z * scg);  f[3] = (_Float16)(A.w * scg);
                f[4] = (_Float16)(Bv.x * scg); f[5] = (_Float16)(Bv.y * scg);
                f[6] = (_Float16)(Bv.z * scg); f[7] = (_Float16)(Bv.w * scg);
                afrag[ti][kc] = f;
            }
        }
    }
    v4f biasv[4];
    float creg[4];
#pragma unroll
    for (int ti = 0; ti < 4; ++ti) {
        const int jloc = jg * 64 + w * 16 + q * 4 + ti;
#pragma unroll
        for (int g = 0; g < 4; ++g) {
            const float s = (g == 2) ? 2.885390082f : -1.442695041f;
            biasv[ti][g] = (bih[g * kH + jloc] + bhh[g * kH + jloc]) * s;
        }
        creg[ti] = c0[(size_t)(bgrp * 16 + lm) * kH + jloc];
    }

    const float bout0 = bout_p[0];
    // in-loop y identity: waves {0,1} -> batch yb0, {2,3} -> yb0+1;
    // lane covers j = (w&1)*256 + ln*4 .. +3 (fragment 8B read from hreg).
    const int j0y = (w & 1) * 256 + ln * 4;
    const int cky = j0y >> 5, jly = j0y & 31;
    const int oy = cky * 1024 +
                   ((((jly >> 3) * 16 + (jg * 2 + (w >> 1))) ^ cky) * 16) +
                   (jly & 7) * 2;
    const float4 ywt4 = *(const float4*)(Wout + j0y);
    // tail identity: threads 0-127 batch0, 128-255 batch1, j = (tid&127)*4
    const float4 wout4 = *(const float4*)(Wout + (tid & 127) * 4);

    // x stager identity (threads 96..255)
    const int st = tid - 96, xb = st & 15, c10 = st >> 4;
    const bool isX = (tid >= 96);
    float4 xr[4];

    auto x_load = [&](int tt) {
        if (isX) {
            const size_t brow = (size_t)(bgrp * 16 + xb) * kT + tt;
            const float* p = (c10 < 8) ? (obs + brow * 128 + c10 * 16)
                                       : (act + brow * 32 + (c10 - 8) * 16);
            xr[0] = *(const float4*)(p);
            xr[1] = *(const float4*)(p + 4);
            xr[2] = *(const float4*)(p + 8);
            xr[3] = *(const float4*)(p + 12);
        }
    };
    auto x_write = [&](char* xbase) {
        if (isX) {
            const int kcx = c10 >> 1;
#pragma unroll
            for (int ii = 0; ii < 2; ++ii) {
                const int qx = (2 * c10 + ii) & 3;
                const int slot = (qx * 16 + xb) ^ kcx;
                float4 a = xr[2 * ii], b = xr[2 * ii + 1];
                v8h f;
                f[0] = (_Float16)a.x; f[1] = (_Float16)a.y;
                f[2] = (_Float16)a.z; f[3] = (_Float16)a.w;
                f[4] = (_Float16)b.x; f[5] = (_Float16)b.y;
                f[6] = (_Float16)b.z; f[7] = (_Float16)b.w;
                *(v8h*)(xbase + kcx * 1024 + slot * 16) = f;
            }
        }
    };

    // ---- preloop: stage x(0) into xbuf[0]; preload x(1) into regs ----
    x_load(0);
    x_write(xbuf[0]);
    x_load(1);
    __syncthreads();

    char* const hfAc = (char*)hfA;
    char* const hfBc = (char*)hfB;

    // publish identity: lane (lm,q) of wave w writes 8B = h of
    // j-local w*16 + q*4 + {0..3}, batch lm:
    const int ckp = jg * 2 + (w >> 1);
    const int qfp = (w & 1) * 2 + (q >> 1);
    const int pofs = ckp * 1024 + (((qfp * 16 + lm) ^ ckp) * 16) + (q & 1) * 8;

#pragma unroll 1
    for (int t = 0; t < kT; ++t) {
        const char* hsrcB = ((t & 1) ? hfBc : hfAc) + (size_t)bgrp * 16384;
        char* hdstB = ((t & 1) ? hfAc : hfBc) + (size_t)bgrp * 16384;
        const char* xcur = xbuf[t & 1];
        char* hreg = hbuf[t & 1];

        // ---- 1. per-wave pipelined poll over the 32 producer-wave flags ----
        if (t > 0) {
            const unsigned tgt = (unsigned)t;
            const unsigned* fp = myflags + (ln & 31);
            unsigned v = ld32sc(fp, sysS);
            while (true) {
                unsigned vn = ld32sc(fp, sysS);
                if (__all((int)(v >= tgt))) break;
                v = vn;
            }
        }

        // ---- 2. issue h-stage loads (verbatim 16KB fragment copy) ----
        ull u[8];
#pragma unroll
        for (int k = 0; k < 4; ++k) {
            const ull* sp = (const ull*)(hsrcB + k * 4096 + tid * 16);
            u[2 * k]     = ld64sc(sp, sysS);
            u[2 * k + 1] = ld64sc(sp + 1, sysS);
        }

        // ---- 3. x-part MFMA (kc 0..4) while h loads are in flight ----
        v4f aacc[4], bacc[4];
#pragma unroll
        for (int ti = 0; ti < 4; ++ti) {
            aacc[ti] = biasv[ti];
            bacc[ti] = v4f{0.f, 0.f, 0.f, 0.f};
        }
#pragma unroll
        for (int kc = 0; kc < 5; ++kc) {
            v8h bfr = *(const v8h*)(xcur + kc * 1024 + (ln ^ kc) * 16);
#pragma unroll
            for (int ti = 0; ti < 4; ++ti)
                aacc[ti] = __builtin_amdgcn_mfma_f32_16x16x32_f16(
                    afrag[ti][kc], bfr, aacc[ti], 0, 0, 0);
        }

        // ---- 4. write staged h to LDS (linear b128); stage x(t+1) ----
#pragma unroll
        for (int k = 0; k < 4; ++k) {
            v2u val = {u[2 * k], u[2 * k + 1]};
            *(v2u*)(hreg + k * 4096 + tid * 16) = val;
        }
        if (t < kT - 1) x_write(xbuf[(t + 1) & 1]);
        __syncthreads();  // S0: h(t) + x(t+1) staged (the only barrier)

        // ---- 5. h-part MFMA (ck 0..15), split-K, 4 tiles per bfr ----
#pragma unroll
        for (int ck = 0; ck < 16; ++ck) {
            v8h bfr = *(const v8h*)(hreg + ck * 1024 + (ln ^ ck) * 16);
            if (ck < 8) {
#pragma unroll
                for (int ti = 0; ti < 4; ++ti)
                    aacc[ti] = __builtin_amdgcn_mfma_f32_16x16x32_f16(
                        afrag[ti][5 + ck], bfr, aacc[ti], 0, 0, 0);
            } else {
#pragma unroll
                for (int ti = 0; ti < 4; ++ti)
                    bacc[ti] = __builtin_amdgcn_mfma_f32_16x16x32_f16(
                        afrag[ti][5 + ck], bfr, bacc[ti], 0, 0, 0);
            }
        }

        // ---- 6. epilogue (4 j's/lane) + ONE 8B fragment publish ----
        union { ull u64; _Float16 h4[4]; } pk;
#pragma unroll
        for (int ti = 0; ti < 4; ++ti) {
            v4f a = aacc[ti] + bacc[ti];
            float iv = __builtin_amdgcn_rcpf(1.0f + __builtin_amdgcn_exp2f(a[0]));
            float fv = __builtin_amdgcn_rcpf(1.0f + __builtin_amdgcn_exp2f(a[1]));
            float gv = fmaf(-2.0f,
                            __builtin_amdgcn_rcpf(__builtin_amdgcn_exp2f(a[2]) + 1.0f),
                            1.0f);
            float ov = __builtin_amdgcn_rcpf(1.0f + __builtin_amdgcn_exp2f(a[3]));
            creg[ti] = fmaf(fv, creg[ti], iv * gv);
            pk.h4[ti] = (_Float16)(ov * tanhff(creg[ti]));
        }
        st64sc((ull*)(hdstB + pofs), pk.u64, sysS);

        // ---- 7. hoist y(t-1) LDS read (lgkm overlaps the publish ack) ----
        ull yraw = 0;
        if (t > 0) yraw = *(const ull*)(hreg + oy);

        asm volatile("s_waitcnt vmcnt(0)" ::: "memory");  // publish ack ONLY
        if (ln == 0) st32sc(myflags + jg * 4 + w, (unsigned)(t + 1), sysS);

        // ---- 8. post-flag shadow: x prefetch, y partials, y finalize ----
        if (t < kT - 2) x_load(t + 2);
        if (t > 0) {
            union { ull uu; _Float16 hh[4]; } cv;
            cv.uu = yraw;
            float p = (float)cv.hh[0] * ywt4.x + (float)cv.hh[1] * ywt4.y +
                      (float)cv.hh[2] * ywt4.z + (float)cv.hh[3] * ywt4.w;
#pragma unroll
            for (int s = 32; s; s >>= 1) p += __shfl_xor(p, s);
            if (ln == 0) ypart[t & 1][w] = p;
        }
        if (t >= 2 && tid == 64) {
            const float* yp = ypart[(t - 1) & 1];
            out[(size_t)yb0 * kT + (t - 2)] = bout0 + yp[0] + yp[1];
        }
        if (t >= 2 && tid == 192) {
            const float* yp = ypart[(t - 1) & 1];
            out[(size_t)(yb0 + 1) * kT + (t - 2)] = bout0 + yp[2] + yp[3];
        }
    }

    // ---- tail: out[510] from pending partials; out[511] from h(T) in hfA ----
    if (tid < 64) {
        const unsigned* fp = myflags + (ln & 31);
        while (true) {
            unsigned v = ld32sc(fp, sysS);
            if (__all((int)(v >= (unsigned)kT))) break;
            __builtin_amdgcn_s_sleep(1);
        }
    }
    __syncthreads();
    {
        const int bsel = jg * 2 + (tid >> 7);       // batch row
        const int j0 = (tid & 127) * 4;
        const int ck = j0 >> 5, jl = j0 & 31, qf = jl >> 3, e0 = jl & 7;
        const int slot = (qf * 16 + bsel) ^ ck;
        union { ull uu; _Float16 h4[4]; } cv;
        cv.uu = ld64sc((const ull*)(hfAc + (size_t)bgrp * 16384 + ck * 1024 +
                                    slot * 16 + e0 * 2), sysS);
        float p = (float)cv.h4[0] * wout4.x + (float)cv.h4[1] * wout4.y +
                  (float)cv.h4[2] * wout4.z + (float)cv.h4[3] * wout4.w;
#pragma unroll
        for (int s = 32; s; s >>= 1) p += __shfl_xor(p, s);
        if (ln == 0) ytail[w] = p;
    }
    __syncthreads();
    if (tid == 64) {
        const float* yp = ypart[1];  // written at step 511
        out[(size_t)yb0 * kT + (kT - 2)] = bout0 + yp[0] + yp[1];
    }
    if (tid == 192) {
        const float* yp = ypart[1];
        out[(size_t)(yb0 + 1) * kT + (kT - 2)] = bout0 + yp[2] + yp[3];
    }
    if (tid == 0) {
        out[(size_t)yb0 * kT + (kT - 1)] = ytail[0] + ytail[1] + bout0;
        out[(size_t)(yb0 + 1) * kT + (kT - 1)] = ytail[2] + ytail[3] + bout0;
    }
}

}  // namespace

extern "C" void kernel_launch(void* const* d_in, const int* in_sizes, int n_in,
                              void* d_out, int out_size, void* d_ws, size_t ws_size,
                              hipStream_t stream) {
    const float* obs  = (const float*)d_in[0];
    const float* act  = (const float*)d_in[1];
    const float* Wih  = (const float*)d_in[2];
    const float* Whh  = (const float*)d_in[3];
    const float* bih  = (const float*)d_in[4];
    const float* bhh  = (const float*)d_in[5];
    const float* Wout = (const float*)d_in[6];
    const float* bout = (const float*)d_in[7];
    const float* h0   = (const float*)d_in[8];
    const float* c0   = (const float*)d_in[9];
    float* out = (float*)d_out;

    char* ws = (char*)d_ws;
    _Float16* hfA = (_Float16*)ws;                 // frag-layout h, 256 KB
    _Float16* hfB = (_Float16*)(ws + 262144);      // frag-layout h, 256 KB
    unsigned* ctrl = (unsigned*)(ws + 524288);     // flags[1024] + regcnt[8] + regtotal

    lstm_init<<<512, 256, 0, stream>>>(h0, hfA, ctrl);
    lstm_persist<<<128, 256, 0, stream>>>(obs, act, Wih, Whh, bih, bhh, Wout, bout,
                                          c0, hfA, hfB, ctrl, out);
}

// Round 9
// 1390.187 us; speedup vs baseline: 1.2998x; 1.2998x over previous
//
#include <hip/hip_runtime.h>
#include <math.h>

// LstmCellRudder persistent MFMA kernel, round 16.
// B=256, T=512, D=160 (obs128+act32), H=512, gates 4H=2048, K=672.
// R15 post-mortem: 4-wave degree-8 spilled (VGPR_Count=256 cap, WRITE_SIZE
// 38MB scratch). The arch-VGPR file caps at 256 for MFMA operands - 336
// fragment regs can't fit. Degree-8 was never actually tested.
// NEW vs R12 (R16 = degree-8 with 8-WAVE blocks; per-wave shape = R12):
//   Grid 128 blocks x 512 threads (8 waves, 1 block/CU -> 2 waves/SIMD).
//   16 rings x 8 blocks; block owns 64 j-cols: 8 waves x 2 tiles
//   (afrag[2][21] = 168 VGPR/wave, ~240 total < 256 cap - no spill).
//   - ring degree 16 -> 8: max-of-8 producer skew, 8 blocks/XCD (L2
//     flag+data port contention halved), x-staging duplication halved.
//   - half the chip idle -> DPM/clock headroom (R14 back-compute: ~705MHz
//     effective; waits dominate).
//   - protocol verbatim from R12/R14: workgroup-scope L2-resident ring
//     stores, per-wave flags (64 = 8 blk x 8 wv), fragment-layout dword
//     publish, pipelined poll, single S0 barrier, exp2-prescaled weights.

namespace {
constexpr int kT = 512, kH = 512;

typedef _Float16 v8h __attribute__((ext_vector_type(8)));
typedef float v4f __attribute__((ext_vector_type(4)));
typedef unsigned long long ull;
typedef ull v2u __attribute__((ext_vector_type(2)));

// Ring loads: L1-bypass. sys -> IF$-coherent; pure -> served by shared L2.
__device__ __forceinline__ ull ld64sc(const ull* p, bool sys) {
    return sys ? __hip_atomic_load(p, __ATOMIC_RELAXED, __HIP_MEMORY_SCOPE_SYSTEM)
               : __hip_atomic_load(p, __ATOMIC_RELAXED, __HIP_MEMORY_SCOPE_AGENT);
}
__device__ __forceinline__ unsigned ld32sc(const unsigned* p, bool sys) {
    return sys ? __hip_atomic_load(p, __ATOMIC_RELAXED, __HIP_MEMORY_SCOPE_SYSTEM)
               : __hip_atomic_load(p, __ATOMIC_RELAXED, __HIP_MEMORY_SCOPE_AGENT);
}
// Ring stores: pure rings stay in the shared XCD L2 (WORKGROUP scope);
// mixed rings write through (SYSTEM).
__device__ __forceinline__ void st32sc(unsigned* p, unsigned v, bool sys) {
    if (sys) __hip_atomic_store(p, v, __ATOMIC_RELAXED, __HIP_MEMORY_SCOPE_SYSTEM);
    else     __hip_atomic_store(p, v, __ATOMIC_RELAXED, __HIP_MEMORY_SCOPE_WORKGROUP);
}
__device__ __forceinline__ unsigned ld_sys32(const unsigned* p) {
    return __hip_atomic_load(p, __ATOMIC_RELAXED, __HIP_MEMORY_SCOPE_SYSTEM);
}

// tanh for the (unscaled) cell state; exp2-based, exact at +-inf.
__device__ __forceinline__ float tanhff(float x) {
    return fmaf(-2.0f,
                __builtin_amdgcn_rcpf(__builtin_amdgcn_exp2f(x * 2.885390082f) + 1.0f),
                1.0f);
}

// h0 -> fragment-layout hfA: per ring 16KB; chunk ck (=j>>5) at ck*1024;
// slot = (qf*16 + b) ^ ck holds halfs e=0..7 = h[b][ck*32 + qf*8 + e].
__global__ void lstm_init(const float* __restrict__ h0, _Float16* __restrict__ hfA,
                          unsigned* __restrict__ ctrl) {
    int i = blockIdx.x * blockDim.x + threadIdx.x;  // 131072 = B*H
    int bb = i >> 9, j = i & 511;
    int bgrp = bb >> 4, b = bb & 15;
    int ck = j >> 5, jl = j & 31, qf = jl >> 3, e = jl & 7;
    int slot = (qf * 16 + b) ^ ck;
    hfA[bgrp * 8192 + ck * 512 + slot * 8 + e] = (_Float16)h0[i];
    if (i < 1152) ctrl[i] = 0u;  // flags[16*64] + regcnt[8] + regtotal
}

__global__ __launch_bounds__(512, 2) void lstm_persist(
    const float* __restrict__ obs, const float* __restrict__ act,
    const float* __restrict__ Wih, const float* __restrict__ Whh,
    const float* __restrict__ bih, const float* __restrict__ bhh,
    const float* __restrict__ Wout, const float* __restrict__ bout_p,
    const float* __restrict__ c0,
    _Float16* __restrict__ hfA, _Float16* __restrict__ hfB,
    unsigned* __restrict__ ctrl, float* __restrict__ out) {

    // LDS: x double buffer 2x5KB, h fragment double buffer 2x16KB.
    __shared__ __align__(16) char xbuf[2][5 * 1024];
    __shared__ __align__(16) char hbuf[2][16 * 1024];
    __shared__ float ypart[2][8];
    __shared__ float ytail[4];
    __shared__ int sh_role[3];  // ring, jg, sys

    const int tid = threadIdx.x;
    const int w = tid >> 6, ln = tid & 63;   // 8 waves
    const int lm = ln & 15, q = ln >> 4;     // MFMA lane decomposition

    unsigned* flags = ctrl;              // [16 rings][64] (8 blk x 8 wv)
    unsigned* regcnt = ctrl + 1024;      // [8]
    unsigned* regtotal = ctrl + 1032;    // [1]

    // ---- runtime XCD-aware role negotiation (groups of 8 blocks) ----
    if (tid == 0) {
        int x = __builtin_amdgcn_s_getreg(20 | (31 << 11)) & 7;  // HW_REG_XCC_ID
        unsigned slot = atomicAdd(&regcnt[x], 1u);
        asm volatile("s_waitcnt vmcnt(0)" ::: "memory");
        atomicAdd(regtotal, 1u);
        while (ld_sys32(regtotal) < 128u) __builtin_amdgcn_s_sleep(8);
        unsigned cnt[8];
#pragma unroll
        for (int i = 0; i < 8; ++i) cnt[i] = ld_sys32(&regcnt[i]);
        int pure_base = 0, total_pure = 0, lbase = 0;
        for (int i = 0; i < 8; ++i) {
            if (i < x) { pure_base += cnt[i] >> 3; lbase += cnt[i] & 7; }
            total_pure += cnt[i] >> 3;
        }
        int px8 = (int)(cnt[x] >> 3) * 8;
        int bg, jv, sv;
        if ((int)slot < px8) {
            bg = pure_base + ((int)slot >> 3); jv = slot & 7; sv = 0;
        } else {
            int lr = lbase + ((int)slot - px8);
            bg = total_pure + (lr >> 3); jv = lr & 7; sv = 1;
        }
        sh_role[0] = bg; sh_role[1] = jv; sh_role[2] = sv;
    }
    __syncthreads();
    const int bgrp = sh_role[0], jg = sh_role[1];  // jg in [0,8)
    const bool sysS = sh_role[2] != 0;
    const int yb0 = bgrp * 16 + jg * 2;            // two output batch rows
    unsigned* myflags = flags + bgrp * 64;

    // ---- persistent A fragments: wave w in [0,8) -> j-local = w*8+jj*2+ti
    // (lane (lm,q) holds gates of j-local = w*8 + q*2 + ti: the two epilogue
    //  halves (ti=0,1) form one fragment dword -> direct publish)
    // Prescale rows: i,f,o by -log2(e); g by +2*log2(e) (exp2 epilogue).
    v8h afrag[2][21];
    {
        const int jj = lm >> 2, gt = lm & 3;
        const float scg = (gt == 2) ? 2.885390082f : -1.442695041f;
#pragma unroll
        for (int ti = 0; ti < 2; ++ti) {
            const int grow = gt * kH + jg * 64 + w * 8 + jj * 2 + ti;
#pragma unroll
            for (int kc = 0; kc < 21; ++kc) {
                const int k0 = kc * 32 + q * 8;
                const float* src = (k0 < 160) ? (Wih + grow * 160 + k0)
                                              : (Whh + (size_t)grow * kH + (k0 - 160));
                float4 A = *(const float4*)src;
                float4 Bv = *(const float4*)(src + 4);
                v8h f;
                f[0] = (_Float16)(A.x * scg);  f[1] = (_Float16)(A.y * scg);
                f[2] = (_Float16)(A.z * scg);  f[3] = (_Float16)(A.w * scg);
                f[4] = (_Float16)(Bv.x * scg); f[5] = (_Float16)(Bv.y * scg);
                f[6] = (_Float16)(Bv.z * scg); f[7] = (_Float16)(Bv.w * scg);
                afrag[ti][kc] = f;
            }
        }
    }
    float biasv[2][4];
    float creg[2];
#pragma unroll
    for (int ti = 0; ti < 2; ++ti) {
        const int jloc = jg * 64 + w * 8 + q * 2 + ti;
#pragma unroll
        for (int g = 0; g < 4; ++g) {
            const float s = (g == 2) ? 2.885390082f : -1.442695041f;
            biasv[ti][g] = (bih[g * kH + jloc] + bhh[g * kH + jloc]) * s;
        }
        creg[ti] = c0[(size_t)(bgrp * 16 + lm) * kH + jloc];
    }

    const float bout0 = bout_p[0];
    // in-loop y identity: threads 0-255 batch jg*2, 256-511 batch jg*2+1;
    // each covers k = 2*(tid&255) (dword from staged hreg).
    const int ky = 2 * (tid & 255);
    const int bloc = jg * 2 + (tid >> 8);
    const int cky = ky >> 5, jly = ky & 31;
    const int oy = cky * 1024 + ((((jly >> 3) * 16 + bloc) ^ cky) * 16) + (jly & 7) * 2;
    const float2 wout2 = *(const float2*)(Wout + ky);
    // tail identity: threads 0-255: batch jg*2 + (tid>>7), j = (tid&127)*4
    float4 wout4 = make_float4(0.f, 0.f, 0.f, 0.f);
    if (tid < 256) wout4 = *(const float4*)(Wout + (tid & 127) * 4);

    // x stager identity (threads 96..255)
    const int st = tid - 96, xb = st & 15, c10 = st >> 4;
    const bool isX = (tid >= 96) && (tid < 256);
    float4 xr[4];

    auto x_load = [&](int tt) {
        if (isX) {
            const size_t brow = (size_t)(bgrp * 16 + xb) * kT + tt;
            const float* p = (c10 < 8) ? (obs + brow * 128 + c10 * 16)
                                       : (act + brow * 32 + (c10 - 8) * 16);
            xr[0] = *(const float4*)(p);
            xr[1] = *(const float4*)(p + 4);
            xr[2] = *(const float4*)(p + 8);
            xr[3] = *(const float4*)(p + 12);
        }
    };
    auto x_write = [&](char* xbase) {
        if (isX) {
            const int kcx = c10 >> 1;
#pragma unroll
            for (int ii = 0; ii < 2; ++ii) {
                const int qx = (2 * c10 + ii) & 3;
                const int slot = (qx * 16 + xb) ^ kcx;
                float4 a = xr[2 * ii], b = xr[2 * ii + 1];
                v8h f;
                f[0] = (_Float16)a.x; f[1] = (_Float16)a.y;
                f[2] = (_Float16)a.z; f[3] = (_Float16)a.w;
                f[4] = (_Float16)b.x; f[5] = (_Float16)b.y;
                f[6] = (_Float16)b.z; f[7] = (_Float16)b.w;
                *(v8h*)(xbase + kcx * 1024 + slot * 16) = f;
            }
        }
    };

    // ---- preloop: stage x(0) into xbuf[0]; preload x(1) into regs ----
    x_load(0);
    x_write(xbuf[0]);
    x_load(1);
    __syncthreads();

    char* const hfAc = (char*)hfA;
    char* const hfBc = (char*)hfB;

    // publish identity: lane (lm,q) of wave w stores the dword holding
    // j = jg*64 + w*8 + q*2 + {0,1}, batch lm:
    //   ck = jg*2 + (w>>2); jl = (w&3)*8 + q*2 + ti; qf = w&3; e0 = q*2.
    const int ckp = jg * 2 + (w >> 2);
    const int pofs = ckp * 1024 + ((((w & 3) * 16 + lm) ^ ckp) * 16) + q * 4;

#pragma unroll 1
    for (int t = 0; t < kT; ++t) {
        const char* hsrcB = ((t & 1) ? hfBc : hfAc) + (size_t)bgrp * 16384;
        char* hdstB = ((t & 1) ? hfAc : hfBc) + (size_t)bgrp * 16384;
        const char* xcur = xbuf[t & 1];
        char* hreg = hbuf[t & 1];

        // ---- 1. per-wave pipelined poll over the 64 producer-wave flags ----
        if (t > 0) {
            const unsigned tgt = (unsigned)t;
            const unsigned* fp = myflags + ln;
            unsigned v = ld32sc(fp, sysS);
            while (true) {
                unsigned vn = ld32sc(fp, sysS);
                if (__all((int)(v >= tgt))) break;
                v = vn;
            }
        }

        // ---- 2. issue h-stage loads (verbatim 16KB copy; 32B/thread) ----
        ull u[4];
        {
            const ull* sp = (const ull*)(hsrcB + tid * 32);
            u[0] = ld64sc(sp + 0, sysS);
            u[1] = ld64sc(sp + 1, sysS);
            u[2] = ld64sc(sp + 2, sysS);
            u[3] = ld64sc(sp + 3, sysS);
        }

        // ---- 3. x-part MFMA (kc 0..4) while h loads are in flight ----
        v4f a0 = {biasv[0][0], biasv[0][1], biasv[0][2], biasv[0][3]};
        v4f a1 = {biasv[1][0], biasv[1][1], biasv[1][2], biasv[1][3]};
#pragma unroll
        for (int kc = 0; kc < 5; ++kc) {
            v8h bfr = *(const v8h*)(xcur + kc * 1024 + (ln ^ kc) * 16);
            a0 = __builtin_amdgcn_mfma_f32_16x16x32_f16(afrag[0][kc], bfr, a0, 0, 0, 0);
            a1 = __builtin_amdgcn_mfma_f32_16x16x32_f16(afrag[1][kc], bfr, a1, 0, 0, 0);
        }

        // ---- 4. write staged h to LDS (linear b128); stage x(t+1) ----
        {
            v2u v0 = {u[0], u[1]}, v1 = {u[2], u[3]};
            *(v2u*)(hreg + tid * 32) = v0;
            *(v2u*)(hreg + tid * 32 + 16) = v1;
        }
        if (t < kT - 1) x_write(xbuf[(t + 1) & 1]);
        __syncthreads();  // S0: h(t) + x(t+1) staged (the only barrier)

        // ---- 5. h-part MFMA (ck 0..15), split-K: 4 independent chains ----
        v4f b0 = {0.f, 0.f, 0.f, 0.f}, b1 = {0.f, 0.f, 0.f, 0.f};
#pragma unroll
        for (int ck = 0; ck < 8; ++ck) {
            v8h bfr = *(const v8h*)(hreg + ck * 1024 + (ln ^ ck) * 16);
            a0 = __builtin_amdgcn_mfma_f32_16x16x32_f16(afrag[0][5 + ck], bfr, a0, 0, 0, 0);
            a1 = __builtin_amdgcn_mfma_f32_16x16x32_f16(afrag[1][5 + ck], bfr, a1, 0, 0, 0);
        }
#pragma unroll
        for (int ck = 8; ck < 16; ++ck) {
            v8h bfr = *(const v8h*)(hreg + ck * 1024 + (ln ^ ck) * 16);
            b0 = __builtin_amdgcn_mfma_f32_16x16x32_f16(afrag[0][5 + ck], bfr, b0, 0, 0, 0);
            b1 = __builtin_amdgcn_mfma_f32_16x16x32_f16(afrag[1][5 + ck], bfr, b1, 0, 0, 0);
        }

        // ---- 6. epilogue (prescaled exp2 activations) + dword publish ----
        union { unsigned u32; _Float16 h2[2]; } pk;
#pragma unroll
        for (int ti = 0; ti < 2; ++ti) {
            v4f a = ti ? (a1 + b1) : (a0 + b0);
            float iv = __builtin_amdgcn_rcpf(1.0f + __builtin_amdgcn_exp2f(a[0]));
            float fv = __builtin_amdgcn_rcpf(1.0f + __builtin_amdgcn_exp2f(a[1]));
            float gv = fmaf(-2.0f,
                            __builtin_amdgcn_rcpf(__builtin_amdgcn_exp2f(a[2]) + 1.0f),
                            1.0f);
            float ov = __builtin_amdgcn_rcpf(1.0f + __builtin_amdgcn_exp2f(a[3]));
            creg[ti] = fmaf(fv, creg[ti], iv * gv);
            pk.h2[ti] = (_Float16)(ov * tanhff(creg[ti]));
        }
        st32sc((unsigned*)(hdstB + pofs), pk.u32, sysS);

        // ---- 7. hoist y(t-1) LDS read (lgkm overlaps the publish ack) ----
        unsigned yraw = 0;
        if (t > 0) yraw = *(const unsigned*)(hreg + oy);

        asm volatile("s_waitcnt vmcnt(0)" ::: "memory");  // publish ack ONLY
        if (ln == 0) st32sc(myflags + jg * 8 + w, (unsigned)(t + 1), sysS);

        // ---- 8. post-flag shadow: x prefetch, y partials, y finalize ----
        if (t < kT - 2) x_load(t + 2);
        if (t > 0) {
            union { unsigned uu; _Float16 hh[2]; } cv;
            cv.uu = yraw;
            float p = (float)cv.hh[0] * wout2.x + (float)cv.hh[1] * wout2.y;
#pragma unroll
            for (int s = 32; s; s >>= 1) p += __shfl_xor(p, s);
            if (ln == 0) ypart[t & 1][w] = p;
        }
        if (t >= 2 && tid == 64) {
            const float* yp = ypart[(t - 1) & 1];
            out[(size_t)yb0 * kT + (t - 2)] = bout0 + yp[0] + yp[1] + yp[2] + yp[3];
        }
        if (t >= 2 && tid == 320) {
            const float* yp = ypart[(t - 1) & 1];
            out[(size_t)(yb0 + 1) * kT + (t - 2)] = bout0 + yp[4] + yp[5] + yp[6] + yp[7];
        }
    }

    // ---- tail: out[510] from pending partials; out[511] from h(T) in hfA ----
    if (tid < 64) {
        const unsigned* fp = myflags + ln;
        while (true) {
            unsigned v = ld32sc(fp, sysS);
            if (__all((int)(v >= (unsigned)kT))) break;
            __builtin_amdgcn_s_sleep(1);
        }
    }
    __syncthreads();
    if (tid < 256) {
        const int bsel = jg * 2 + (tid >> 7);       // batch row
        const int j0 = (tid & 127) * 4;
        const int ck = j0 >> 5, jl = j0 & 31, qf = jl >> 3, e0 = jl & 7;
        const int slot = (qf * 16 + bsel) ^ ck;
        union { ull uu; _Float16 h4[4]; } cv;
        cv.uu = ld64sc((const ull*)(hfAc + (size_t)bgrp * 16384 + ck * 1024 +
                                    slot * 16 + e0 * 2), sysS);
        float p = (float)cv.h4[0] * wout4.x + (float)cv.h4[1] * wout4.y +
                  (float)cv.h4[2] * wout4.z + (float)cv.h4[3] * wout4.w;
#pragma unroll
        for (int s = 32; s; s >>= 1) p += __shfl_xor(p, s);
        if (ln == 0) ytail[w] = p;
    }
    __syncthreads();
    if (tid == 64) {
        const float* yp = ypart[1];  // written at step 511
        out[(size_t)yb0 * kT + (kT - 2)] = bout0 + yp[0] + yp[1] + yp[2] + yp[3];
    }
    if (tid == 320) {
        const float* yp = ypart[1];
        out[(size_t)(yb0 + 1) * kT + (kT - 2)] = bout0 + yp[4] + yp[5] + yp[6] + yp[7];
    }
    if (tid == 0) {
        out[(size_t)yb0 * kT + (kT - 1)] = ytail[0] + ytail[1] + bout0;
        out[(size_t)(yb0 + 1) * kT + (kT - 1)] = ytail[2] + ytail[3] + bout0;
    }
}

}  // namespace

extern "C" void kernel_launch(void* const* d_in, const int* in_sizes, int n_in,
                              void* d_out, int out_size, void* d_ws, size_t ws_size,
                              hipStream_t stream) {
    const float* obs  = (const float*)d_in[0];
    const float* act  = (const float*)d_in[1];
    const float* Wih  = (const float*)d_in[2];
    const float* Whh  = (const float*)d_in[3];
    const float* bih  = (const float*)d_in[4];
    const float* bhh  = (const float*)d_in[5];
    const float* Wout = (const float*)d_in[6];
    const float* bout = (const float*)d_in[7];
    const float* h0   = (const float*)d_in[8];
    const float* c0   = (const float*)d_in[9];
    float* out = (float*)d_out;

    char* ws = (char*)d_ws;
    _Float16* hfA = (_Float16*)ws;                 // frag-layout h, 256 KB
    _Float16* hfB = (_Float16*)(ws + 262144);      // frag-layout h, 256 KB
    unsigned* ctrl = (unsigned*)(ws + 524288);     // flags[1024] + regcnt[8] + regtotal

    lstm_init<<<512, 256, 0, stream>>>(h0, hfA, ctrl);
    lstm_persist<<<128, 512, 0, stream>>>(obs, act, Wih, Whh, bih, bhh, Wout, bout,
                                          c0, hfA, hfB, ctrl, out);
}